// Round 5
// baseline (277.274 us; speedup 1.0000x reference)
//
#include <hip/hip_runtime.h>
#include <hip/hip_bf16.h>

typedef __attribute__((ext_vector_type(4))) float f32x4;
typedef __attribute__((ext_vector_type(8))) short bf16x8;   // 8 bf16 = 4 VGPRs
typedef unsigned short u16;
typedef __attribute__((ext_vector_type(4))) u16 u16x4;

// Problem constants
// g [2,2048,1024] f32 ; Wq/Wk [12,64,1024] f32 ; Whn [4096,1024] f32 ; out = scalar f32

// workspace layout (bytes)
#define OFF_GB    ((size_t)0)                    // g bf16      [4096][1024]  8388608
#define OFF_WQB   ((size_t)8388608)              // (beta*log2e)*Wq bf16 [768][1024]
#define OFF_WKB   ((size_t)(8388608+1572864))    // Wk bf16      [768][1024]
#define OFF_WHNB  ((size_t)(8388608+2*1572864))  // Whn bf16    [4096][1024]  8388608
#define OFF_QB    (OFF_WHNB + 8388608)           // q bf16 [24][2048][64] per-head
#define OFF_KB    (OFF_QB + 6291456)             // k bf16 [24][2048][64] per-head

__device__ __forceinline__ u16 f2bf(float f) {
  union { float f; unsigned u; } x; x.f = f;
  unsigned u = x.u;
  u += 0x7fffu + ((u >> 16) & 1u);   // RNE
  return (u16)(u >> 16);
}

// ---------------- fused f32 -> bf16 conversion (beta*log2e folded into Wq) ----------------
__global__ __launch_bounds__(256) void convert_all(
    const float* __restrict__ g, const float* __restrict__ wq,
    const float* __restrict__ wk, const float* __restrict__ whn,
    u16* __restrict__ gB, u16* __restrict__ wqB, u16* __restrict__ wkB, u16* __restrict__ whnB)
{
  const int NG = 1048576;   // 4194304/4 float4 quads
  const int NW = 196608;    // 786432/4
  const int total = NG + 2 * NW + NG;
  for (int i = blockIdx.x * blockDim.x + threadIdx.x; i < total; i += gridDim.x * blockDim.x) {
    const float4* src; u16* dst; int j; float scale = 1.0f;
    if (i < NG)              { src = (const float4*)g;   dst = gB;   j = i; }
    else if (i < NG + NW)    { src = (const float4*)wq;  dst = wqB;  j = i - NG;
                               scale = 0.125f * 1.44269504089f; }   // beta * log2(e)
    else if (i < NG + 2*NW)  { src = (const float4*)wk;  dst = wkB;  j = i - NG - NW; }
    else                     { src = (const float4*)whn; dst = whnB; j = i - NG - 2*NW; }
    float4 v = src[j];
    u16x4 o;
    o.x = f2bf(v.x * scale); o.y = f2bf(v.y * scale);
    o.z = f2bf(v.z * scale); o.w = f2bf(v.w * scale);
    *(u16x4*)(dst + (size_t)j * 4) = o;
  }
}

// ---------------- 128x128 tile GEMM (m97 structure), q/k projection ----------------
// bn<6 -> Wq->qB, else Wk->kB; store bf16 into per-head layout [z][n][64]
__global__ __launch_bounds__(256) void gemm_bt(
    const u16* __restrict__ A, const u16* __restrict__ B0, const u16* __restrict__ B1,
    u16* __restrict__ C0, u16* __restrict__ C1, int K)
{
  __shared__ u16 lA[128 * 64];
  __shared__ u16 lB[128 * 64];
  const int tid = threadIdx.x;
  const int lane = tid & 63;
  const int w = tid >> 6;          // wave 0..3
  const int bm = blockIdx.x;
  const int bn = blockIdx.y;

  const u16* Bp; u16* Cp; int bcol0;
  if (bn < 6) { Bp = B0; Cp = C0; bcol0 = bn * 128; }
  else        { Bp = B1; Cp = C1; bcol0 = (bn - 6) * 128; }
  const int arow0 = bm * 128;
  const int wr = w >> 1, wc = w & 1;
  const int l15 = lane & 15, lg = lane >> 4;

  f32x4 acc[4][4];
  const f32x4 zz = {0.f, 0.f, 0.f, 0.f};
#pragma unroll
  for (int m = 0; m < 4; m++)
#pragma unroll
    for (int n = 0; n < 4; n++) acc[m][n] = zz;

#define STAGE(KT) do {                                                                     \
    _Pragma("unroll")                                                                      \
    for (int i = 0; i < 4; i++) {                                                          \
      int rloc = w * 32 + i * 8 + (lane >> 3);                                             \
      int cb   = (((lane & 7) ^ (rloc & 7)) << 4);                                         \
      const char* srcA = (const char*)A + (((size_t)(arow0 + rloc)) * K + (KT) * 64) * 2 + cb; \
      __builtin_amdgcn_global_load_lds((const __attribute__((address_space(1))) void*)srcA, \
          (__attribute__((address_space(3))) void*)((char*)lA + (w * 32 + i * 8) * 128), 16, 0, 0); \
      const char* srcB = (const char*)Bp + (((size_t)(bcol0 + rloc)) * K + (KT) * 64) * 2 + cb; \
      __builtin_amdgcn_global_load_lds((const __attribute__((address_space(1))) void*)srcB, \
          (__attribute__((address_space(3))) void*)((char*)lB + (w * 32 + i * 8) * 128), 16, 0, 0); \
    }                                                                                      \
  } while (0)

  STAGE(0);
  const int nkt = K / 64;
  for (int kt = 0; kt < nkt; ++kt) {
    __syncthreads();
    bf16x8 a0[4], a1[4], b0[4], b1[4];
#pragma unroll
    for (int m = 0; m < 4; m++) {
      int row = wr * 64 + m * 16 + l15;
      const char* base = (const char*)lA + row * 128;
      int sw = (row & 7) << 4;
      a0[m] = *(const bf16x8*)(base + ((lg * 16) ^ sw));
      a1[m] = *(const bf16x8*)(base + ((64 + lg * 16) ^ sw));
    }
#pragma unroll
    for (int n = 0; n < 4; n++) {
      int row = wc * 64 + n * 16 + l15;
      const char* base = (const char*)lB + row * 128;
      int sw = (row & 7) << 4;
      b0[n] = *(const bf16x8*)(base + ((lg * 16) ^ sw));
      b1[n] = *(const bf16x8*)(base + ((64 + lg * 16) ^ sw));
    }
    __syncthreads();
    if (kt + 1 < nkt) STAGE(kt + 1);
#pragma unroll
    for (int m = 0; m < 4; m++)
#pragma unroll
      for (int n = 0; n < 4; n++) {
        acc[m][n] = __builtin_amdgcn_mfma_f32_16x16x32_bf16(a0[m], b0[n], acc[m][n], 0, 0, 0);
        acc[m][n] = __builtin_amdgcn_mfma_f32_16x16x32_bf16(a1[m], b1[n], acc[m][n], 0, 0, 0);
      }
  }
  // C/D layout (m89-verified): col = lane&15, row = (lane>>4)*4 + reg
  // per-head dst: row = b*2048+nn, col = h*64+d  ->  ((b*12+h)*2048 + nn)*64 + d
#pragma unroll
  for (int m = 0; m < 4; m++)
#pragma unroll
    for (int n = 0; n < 4; n++)
#pragma unroll
      for (int r = 0; r < 4; r++) {
        int row = arow0 + wr * 64 + m * 16 + lg * 4 + r;
        int col = bcol0 + wc * 64 + n * 16 + l15;
        size_t dst = ((((size_t)(row >> 11) * 12 + (col >> 6)) << 11) + (row & 2047)) * 64 + (col & 63);
        Cp[dst] = f2bf(acc[m][n][r]);
      }
#undef STAGE
}

// ---------------- Hopfield energy: 256x256-tile 8-phase GEMM (T2+T3+T4+T5) ----------------
__global__ __launch_bounds__(512, 2) void hop_gemm8(
    const u16* __restrict__ A, const u16* __restrict__ Bm, float* __restrict__ out)
{
  __shared__ __align__(16) u16 lds[2][2][2][128][64];   // [buf][mat][half][row][col]
  const int tid = threadIdx.x;
  const int lane = tid & 63, w = tid >> 6;
  const int wr = w >> 2, wc = w & 3;
  const int l15 = lane & 15, lg = lane >> 4;
  const int am0 = blockIdx.x * 256;
  const int bn0 = blockIdx.y * 256;
  constexpr int nkt = 16;   // K = 1024, BK = 64

  f32x4 acc[8][4];
  const f32x4 zz = {0.f, 0.f, 0.f, 0.f};
#pragma unroll
  for (int i = 0; i < 8; i++)
#pragma unroll
    for (int j = 0; j < 4; j++) acc[i][j] = zz;

#define HSTAGE(KT, MAT, H) do {                                                            \
    const u16* s_ = (MAT) ? Bm : A;                                                        \
    int rb_ = ((MAT) ? bn0 : am0) + (H) * 128;                                             \
    char* d0_ = (char*)&lds[(KT) & 1][(MAT)][(H)][0][0];                                   \
    _Pragma("unroll")                                                                      \
    for (int q_ = 0; q_ < 2; q_++) {                                                       \
      int r_ = q_ * 64 + (tid >> 3);                                                       \
      int cb_ = ((tid & 7) * 16) ^ ((r_ & 7) << 4);                                        \
      const char* g_ = (const char*)s_ + (size_t)(rb_ + r_) * 2048 + (KT) * 128 + cb_;     \
      __builtin_amdgcn_global_load_lds((const __attribute__((address_space(1))) void*)g_,  \
          (__attribute__((address_space(3))) void*)(d0_ + q_ * 8192 + tid * 16), 16, 0, 0);\
    }                                                                                      \
  } while (0)

#define LDA_F(DST, P, I, S) do {                                                           \
    int rh_ = ((I) & 3) * 32 + wr * 16 + l15;                                              \
    const char* b_ = (const char*)&lds[(P)][0][(I) >> 2][0][0] + rh_ * 128;                \
    DST = *(const bf16x8*)(b_ + (((S) * 64 + lg * 16) ^ ((rh_ & 7) << 4)));                \
  } while (0)
#define LDB_F(DST, P, J, S) do {                                                           \
    int rh_ = ((J) & 1) * 64 + wc * 16 + l15;                                              \
    const char* b_ = (const char*)&lds[(P)][1][(J) >> 1][0][0] + rh_ * 128;                \
    DST = *(const bf16x8*)(b_ + (((S) * 64 + lg * 16) ^ ((rh_ & 7) << 4)));                \
  } while (0)

  // prologue: tile0 all 4 halves, tile1 first 3 halves -> 14 loads; drain to 6 (tile0 done)
  HSTAGE(0, 0, 0); HSTAGE(0, 1, 0); HSTAGE(0, 1, 1); HSTAGE(0, 0, 1);
  HSTAGE(1, 0, 0); HSTAGE(1, 1, 0); HSTAGE(1, 1, 1);
  asm volatile("s_waitcnt vmcnt(6)" ::: "memory");
  __builtin_amdgcn_s_barrier();

  bf16x8 af[4][2], bf[4][2];

#pragma unroll 2
  for (int t = 0; t < nkt; ++t) {
    const int p = t & 1;
    // ---- phase 0: ds_read A-h0 (m0-3) + B-h0 (n0-1); stage A-h1(t+1) ----
#pragma unroll
    for (int m = 0; m < 4; m++) { LDA_F(af[m][0], p, m, 0); LDA_F(af[m][1], p, m, 1); }
#pragma unroll
    for (int n = 0; n < 2; n++) { LDB_F(bf[n][0], p, n, 0); LDB_F(bf[n][1], p, n, 1); }
    if (t + 1 < nkt) HSTAGE(t + 1, 0, 1);
    __builtin_amdgcn_s_barrier();
    __builtin_amdgcn_s_setprio(1);
#pragma unroll
    for (int m = 0; m < 4; m++)
#pragma unroll
      for (int n = 0; n < 2; n++) {
        acc[m][n] = __builtin_amdgcn_mfma_f32_16x16x32_bf16(af[m][0], bf[n][0], acc[m][n], 0, 0, 0);
        acc[m][n] = __builtin_amdgcn_mfma_f32_16x16x32_bf16(af[m][1], bf[n][1], acc[m][n], 0, 0, 0);
      }
    __builtin_amdgcn_s_setprio(0);
    __builtin_amdgcn_s_barrier();
    // ---- phase 1: ds_read B-h1 (n2-3); stage A-h0(t+2) ----
#pragma unroll
    for (int n = 2; n < 4; n++) { LDB_F(bf[n][0], p, n, 0); LDB_F(bf[n][1], p, n, 1); }
    if (t + 2 < nkt) HSTAGE(t + 2, 0, 0);
    __builtin_amdgcn_s_barrier();
    __builtin_amdgcn_s_setprio(1);
#pragma unroll
    for (int m = 0; m < 4; m++)
#pragma unroll
      for (int n = 2; n < 4; n++) {
        acc[m][n] = __builtin_amdgcn_mfma_f32_16x16x32_bf16(af[m][0], bf[n][0], acc[m][n], 0, 0, 0);
        acc[m][n] = __builtin_amdgcn_mfma_f32_16x16x32_bf16(af[m][1], bf[n][1], acc[m][n], 0, 0, 0);
      }
    __builtin_amdgcn_s_setprio(0);
    __builtin_amdgcn_s_barrier();
    // ---- phase 2: ds_read A-h1 (m4-7, reuse af); stage B-h0(t+2) ----
#pragma unroll
    for (int m = 0; m < 4; m++) { LDA_F(af[m][0], p, m + 4, 0); LDA_F(af[m][1], p, m + 4, 1); }
    if (t + 2 < nkt) HSTAGE(t + 2, 1, 0);
    __builtin_amdgcn_s_barrier();
    __builtin_amdgcn_s_setprio(1);
#pragma unroll
    for (int m = 0; m < 4; m++)
#pragma unroll
      for (int n = 2; n < 4; n++) {
        acc[m + 4][n] = __builtin_amdgcn_mfma_f32_16x16x32_bf16(af[m][0], bf[n][0], acc[m + 4][n], 0, 0, 0);
        acc[m + 4][n] = __builtin_amdgcn_mfma_f32_16x16x32_bf16(af[m][1], bf[n][1], acc[m + 4][n], 0, 0, 0);
      }
    __builtin_amdgcn_s_setprio(0);
    __builtin_amdgcn_s_barrier();
    // ---- phase 3: stage B-h1(t+2); MFMA m4-7 x n0-1; boundary vmcnt + barrier ----
    if (t + 2 < nkt) HSTAGE(t + 2, 1, 1);
    __builtin_amdgcn_s_barrier();
    __builtin_amdgcn_s_setprio(1);
#pragma unroll
    for (int m = 0; m < 4; m++)
#pragma unroll
      for (int n = 0; n < 2; n++) {
        acc[m + 4][n] = __builtin_amdgcn_mfma_f32_16x16x32_bf16(af[m][0], bf[n][0], acc[m + 4][n], 0, 0, 0);
        acc[m + 4][n] = __builtin_amdgcn_mfma_f32_16x16x32_bf16(af[m][1], bf[n][1], acc[m + 4][n], 0, 0, 0);
      }
    __builtin_amdgcn_s_setprio(0);
    if (t < nkt - 2)       asm volatile("s_waitcnt vmcnt(6)" ::: "memory");
    else if (t == nkt - 2) asm volatile("s_waitcnt vmcnt(0)" ::: "memory");
    __builtin_amdgcn_s_barrier();
  }
#undef HSTAGE
#undef LDA_F
#undef LDB_F

  // epilogue: -0.5 * sum(relu(c)^2), wave-reduce, one atomic per wave
  float loc = 0.f;
#pragma unroll
  for (int i = 0; i < 8; i++)
#pragma unroll
    for (int j = 0; j < 4; j++)
#pragma unroll
      for (int r = 0; r < 4; r++) {
        float v = acc[i][j][r];
        loc += (v > 0.f) ? v * v : 0.f;
      }
#pragma unroll
  for (int mask = 32; mask; mask >>= 1) loc += __shfl_xor(loc, mask, 64);
  if (lane == 0) atomicAdd(out, -0.5f * loc);
}

// ---------------- scores + logsumexp: barrier-free L2 streaming ----------------
// q/k per-head [z][2048][64] bf16. grid (qt=32, z=24), 4 waves/block; each wave owns
// 16 q-rows and streams all 2048 keys straight from L2 (16-row fragment pair = two
// coalesced 1KB loads). Scores are already in log2-domain (beta*log2e folded into Wq),
// so exp2 is a single native v_exp_f32. No LDS, no barriers.
__global__ __launch_bounds__(256) void scores_lse(
    const u16* __restrict__ qB, const u16* __restrict__ kB, float* __restrict__ out)
{
  const int qt = blockIdx.x;
  const int z  = blockIdx.y;          // b*12+h
  const int tid = threadIdx.x, lane = tid & 63, w = tid >> 6;
  const int l15 = lane & 15, lg = lane >> 4;

  const u16* qp = qB + ((size_t)z * 2048 + qt * 64 + w * 16 + l15) * 64 + lg * 8;
  bf16x8 qf0 = *(const bf16x8*)qp;          // dims 0..31 slice
  bf16x8 qf1 = *(const bf16x8*)(qp + 32);   // dims 32..63 slice

  const u16* kbase = kB + (size_t)z * 2048 * 64 + (size_t)l15 * 64 + lg * 8;

  f32x4 sacc = {0.f, 0.f, 0.f, 0.f};   // reg r: q-row lg*4+r, key-col l15
  const f32x4 zz = {0.f, 0.f, 0.f, 0.f};
#pragma unroll 8
  for (int ks = 0; ks < 128; ++ks) {
    const u16* kp = kbase + ks * 1024;        // 16 key-rows x 64 dims
    bf16x8 b0 = *(const bf16x8*)kp;
    bf16x8 b1 = *(const bf16x8*)(kp + 32);
    f32x4 s = zz;
    s = __builtin_amdgcn_mfma_f32_16x16x32_bf16(qf0, b0, s, 0, 0, 0);
    s = __builtin_amdgcn_mfma_f32_16x16x32_bf16(qf1, b1, s, 0, 0, 0);
    sacc[0] += __builtin_amdgcn_exp2f(s[0]);
    sacc[1] += __builtin_amdgcn_exp2f(s[1]);
    sacc[2] += __builtin_amdgcn_exp2f(s[2]);
    sacc[3] += __builtin_amdgcn_exp2f(s[3]);
  }

  // reduce over the 16 key-columns (lanes sharing lg)
#pragma unroll
  for (int mask = 8; mask; mask >>= 1) {
    sacc[0] += __shfl_xor(sacc[0], mask, 64);
    sacc[1] += __shfl_xor(sacc[1], mask, 64);
    sacc[2] += __shfl_xor(sacc[2], mask, 64);
    sacc[3] += __shfl_xor(sacc[3], mask, 64);
  }
  float part = 0.f;
  if (l15 == 0) {
    // v_log_f32 is natively log2
    part = __builtin_amdgcn_logf(sacc[0]) + __builtin_amdgcn_logf(sacc[1]) +
           __builtin_amdgcn_logf(sacc[2]) + __builtin_amdgcn_logf(sacc[3]);
  }
  part += __shfl_xor(part, 16, 64);
  part += __shfl_xor(part, 32, 64);
  // e_attn = -(1/beta)*sum(ln(sumexp)) = -8*ln2*sum(log2(sum2exp))
  if (lane == 0) atomicAdd(out, -5.5451774444795625f * part);
}

extern "C" void kernel_launch(void* const* d_in, const int* in_sizes, int n_in,
                              void* d_out, int out_size, void* d_ws, size_t ws_size,
                              hipStream_t stream)
{
  const float* g   = (const float*)d_in[0];
  const float* Wq  = (const float*)d_in[1];
  const float* Wk  = (const float*)d_in[2];
  const float* Whn = (const float*)d_in[3];
  float* out = (float*)d_out;
  char* ws = (char*)d_ws;

  u16* gB   = (u16*)(ws + OFF_GB);
  u16* wqB  = (u16*)(ws + OFF_WQB);
  u16* wkB  = (u16*)(ws + OFF_WKB);
  u16* whnB = (u16*)(ws + OFF_WHNB);
  u16* qB   = (u16*)(ws + OFF_QB);
  u16* kB   = (u16*)(ws + OFF_KB);

  (void)hipMemsetAsync(out, 0, sizeof(float), stream);

  convert_all<<<2048, 256, 0, stream>>>(g, Wq, Wk, Whn, gB, wqB, wkB, whnB);
  // q and k projections fused in one launch: grid.y 0..5 -> q, 6..11 -> k
  gemm_bt<<<dim3(32, 12), 256, 0, stream>>>(gB, wqB, wkB, qB, kB, 1024);
  // Hopfield energy: 256^2 8-phase
  hop_gemm8<<<dim3(16, 16), 512, 0, stream>>>(gB, whnB, out);
  // attention logsumexp (barrier-free L2 streaming)
  scores_lse<<<dim3(32, 24), 256, 0, stream>>>(qB, kB, out);
}

// Round 6
// 208.464 us; speedup vs baseline: 1.3301x; 1.3301x over previous
//
#include <hip/hip_runtime.h>
#include <hip/hip_bf16.h>

typedef __attribute__((ext_vector_type(4))) float f32x4;
typedef __attribute__((ext_vector_type(8))) short bf16x8;   // 8 bf16 = 4 VGPRs
typedef unsigned short u16;
typedef __attribute__((ext_vector_type(4))) u16 u16x4;

// Problem constants
// g [2,2048,1024] f32 ; Wq/Wk [12,64,1024] f32 ; Whn [4096,1024] f32 ; out = scalar f32

// workspace layout (bytes)
#define OFF_GB    ((size_t)0)                    // g bf16      [4096][1024]  8388608
#define OFF_WQB   ((size_t)8388608)              // (beta*log2e)*Wq bf16 [768][1024]
#define OFF_WKB   ((size_t)(8388608+1572864))    // Wk bf16      [768][1024]
#define OFF_WHNB  ((size_t)(8388608+2*1572864))  // Whn bf16    [4096][1024]  8388608
#define OFF_QB    (OFF_WHNB + 8388608)           // q bf16 [24][2048][64] per-head
#define OFF_KB    (OFF_QB + 6291456)             // k bf16 [24][2048][64] per-head

__device__ __forceinline__ u16 f2bf(float f) {
  union { float f; unsigned u; } x; x.f = f;
  unsigned u = x.u;
  u += 0x7fffu + ((u >> 16) & 1u);   // RNE
  return (u16)(u >> 16);
}

// ---------------- fused f32 -> bf16 conversion (beta*log2e folded into Wq) ----------------
__global__ __launch_bounds__(256) void convert_all(
    const float* __restrict__ g, const float* __restrict__ wq,
    const float* __restrict__ wk, const float* __restrict__ whn,
    u16* __restrict__ gB, u16* __restrict__ wqB, u16* __restrict__ wkB, u16* __restrict__ whnB)
{
  const int NG = 1048576;   // 4194304/4 float4 quads
  const int NW = 196608;    // 786432/4
  const int total = NG + 2 * NW + NG;
  for (int i = blockIdx.x * blockDim.x + threadIdx.x; i < total; i += gridDim.x * blockDim.x) {
    const float4* src; u16* dst; int j; float scale = 1.0f;
    if (i < NG)              { src = (const float4*)g;   dst = gB;   j = i; }
    else if (i < NG + NW)    { src = (const float4*)wq;  dst = wqB;  j = i - NG;
                               scale = 0.125f * 1.44269504089f; }   // beta * log2(e)
    else if (i < NG + 2*NW)  { src = (const float4*)wk;  dst = wkB;  j = i - NG - NW; }
    else                     { src = (const float4*)whn; dst = whnB; j = i - NG - 2*NW; }
    float4 v = src[j];
    u16x4 o;
    o.x = f2bf(v.x * scale); o.y = f2bf(v.y * scale);
    o.z = f2bf(v.z * scale); o.w = f2bf(v.w * scale);
    *(u16x4*)(dst + (size_t)j * 4) = o;
  }
}

// ---------------- 128x128 tile GEMM (m97 structure), q/k projection ----------------
// bn<6 -> Wq->qB, else Wk->kB; store bf16 into per-head layout [z][n][64]
__global__ __launch_bounds__(256) void gemm_bt(
    const u16* __restrict__ A, const u16* __restrict__ B0, const u16* __restrict__ B1,
    u16* __restrict__ C0, u16* __restrict__ C1, int K)
{
  __shared__ u16 lA[128 * 64];
  __shared__ u16 lB[128 * 64];
  const int tid = threadIdx.x;
  const int lane = tid & 63;
  const int w = tid >> 6;          // wave 0..3
  const int bm = blockIdx.x;
  const int bn = blockIdx.y;

  const u16* Bp; u16* Cp; int bcol0;
  if (bn < 6) { Bp = B0; Cp = C0; bcol0 = bn * 128; }
  else        { Bp = B1; Cp = C1; bcol0 = (bn - 6) * 128; }
  const int arow0 = bm * 128;
  const int wr = w >> 1, wc = w & 1;
  const int l15 = lane & 15, lg = lane >> 4;

  f32x4 acc[4][4];
  const f32x4 zz = {0.f, 0.f, 0.f, 0.f};
#pragma unroll
  for (int m = 0; m < 4; m++)
#pragma unroll
    for (int n = 0; n < 4; n++) acc[m][n] = zz;

#define STAGE(KT) do {                                                                     \
    _Pragma("unroll")                                                                      \
    for (int i = 0; i < 4; i++) {                                                          \
      int rloc = w * 32 + i * 8 + (lane >> 3);                                             \
      int cb   = (((lane & 7) ^ (rloc & 7)) << 4);                                         \
      const char* srcA = (const char*)A + (((size_t)(arow0 + rloc)) * K + (KT) * 64) * 2 + cb; \
      __builtin_amdgcn_global_load_lds((const __attribute__((address_space(1))) void*)srcA, \
          (__attribute__((address_space(3))) void*)((char*)lA + (w * 32 + i * 8) * 128), 16, 0, 0); \
      const char* srcB = (const char*)Bp + (((size_t)(bcol0 + rloc)) * K + (KT) * 64) * 2 + cb; \
      __builtin_amdgcn_global_load_lds((const __attribute__((address_space(1))) void*)srcB, \
          (__attribute__((address_space(3))) void*)((char*)lB + (w * 32 + i * 8) * 128), 16, 0, 0); \
    }                                                                                      \
  } while (0)

  STAGE(0);
  const int nkt = K / 64;
  for (int kt = 0; kt < nkt; ++kt) {
    __syncthreads();
    bf16x8 a0[4], a1[4], b0[4], b1[4];
#pragma unroll
    for (int m = 0; m < 4; m++) {
      int row = wr * 64 + m * 16 + l15;
      const char* base = (const char*)lA + row * 128;
      int sw = (row & 7) << 4;
      a0[m] = *(const bf16x8*)(base + ((lg * 16) ^ sw));
      a1[m] = *(const bf16x8*)(base + ((64 + lg * 16) ^ sw));
    }
#pragma unroll
    for (int n = 0; n < 4; n++) {
      int row = wc * 64 + n * 16 + l15;
      const char* base = (const char*)lB + row * 128;
      int sw = (row & 7) << 4;
      b0[n] = *(const bf16x8*)(base + ((lg * 16) ^ sw));
      b1[n] = *(const bf16x8*)(base + ((64 + lg * 16) ^ sw));
    }
    __syncthreads();
    if (kt + 1 < nkt) STAGE(kt + 1);
#pragma unroll
    for (int m = 0; m < 4; m++)
#pragma unroll
      for (int n = 0; n < 4; n++) {
        acc[m][n] = __builtin_amdgcn_mfma_f32_16x16x32_bf16(a0[m], b0[n], acc[m][n], 0, 0, 0);
        acc[m][n] = __builtin_amdgcn_mfma_f32_16x16x32_bf16(a1[m], b1[n], acc[m][n], 0, 0, 0);
      }
  }
  // C/D layout (m89-verified): col = lane&15, row = (lane>>4)*4 + reg
  // per-head dst: row = b*2048+nn, col = h*64+d  ->  ((b*12+h)*2048 + nn)*64 + d
#pragma unroll
  for (int m = 0; m < 4; m++)
#pragma unroll
    for (int n = 0; n < 4; n++)
#pragma unroll
      for (int r = 0; r < 4; r++) {
        int row = arow0 + wr * 64 + m * 16 + lg * 4 + r;
        int col = bcol0 + wc * 64 + n * 16 + l15;
        size_t dst = ((((size_t)(row >> 11) * 12 + (col >> 6)) << 11) + (row & 2047)) * 64 + (col & 63);
        Cp[dst] = f2bf(acc[m][n][r]);
      }
#undef STAGE
}

// ---------------- Hopfield energy: 256x256-tile 8-phase GEMM (T2+T3+T4+T5) ----------------
__global__ __launch_bounds__(512, 2) void hop_gemm8(
    const u16* __restrict__ A, const u16* __restrict__ Bm, float* __restrict__ out)
{
  __shared__ __align__(16) u16 lds[2][2][2][128][64];   // [buf][mat][half][row][col]
  const int tid = threadIdx.x;
  const int lane = tid & 63, w = tid >> 6;
  const int wr = w >> 2, wc = w & 3;
  const int l15 = lane & 15, lg = lane >> 4;
  const int am0 = blockIdx.x * 256;
  const int bn0 = blockIdx.y * 256;
  constexpr int nkt = 16;   // K = 1024, BK = 64

  f32x4 acc[8][4];
  const f32x4 zz = {0.f, 0.f, 0.f, 0.f};
#pragma unroll
  for (int i = 0; i < 8; i++)
#pragma unroll
    for (int j = 0; j < 4; j++) acc[i][j] = zz;

#define HSTAGE(KT, MAT, H) do {                                                            \
    const u16* s_ = (MAT) ? Bm : A;                                                        \
    int rb_ = ((MAT) ? bn0 : am0) + (H) * 128;                                             \
    char* d0_ = (char*)&lds[(KT) & 1][(MAT)][(H)][0][0];                                   \
    _Pragma("unroll")                                                                      \
    for (int q_ = 0; q_ < 2; q_++) {                                                       \
      int r_ = q_ * 64 + (tid >> 3);                                                       \
      int cb_ = ((tid & 7) * 16) ^ ((r_ & 7) << 4);                                        \
      const char* g_ = (const char*)s_ + (size_t)(rb_ + r_) * 2048 + (KT) * 128 + cb_;     \
      __builtin_amdgcn_global_load_lds((const __attribute__((address_space(1))) void*)g_,  \
          (__attribute__((address_space(3))) void*)(d0_ + q_ * 8192 + tid * 16), 16, 0, 0);\
    }                                                                                      \
  } while (0)

#define LDA_F(DST, P, I, S) do {                                                           \
    int rh_ = ((I) & 3) * 32 + wr * 16 + l15;                                              \
    const char* b_ = (const char*)&lds[(P)][0][(I) >> 2][0][0] + rh_ * 128;                \
    DST = *(const bf16x8*)(b_ + (((S) * 64 + lg * 16) ^ ((rh_ & 7) << 4)));                \
  } while (0)
#define LDB_F(DST, P, J, S) do {                                                           \
    int rh_ = ((J) & 1) * 64 + wc * 16 + l15;                                              \
    const char* b_ = (const char*)&lds[(P)][1][(J) >> 1][0][0] + rh_ * 128;                \
    DST = *(const bf16x8*)(b_ + (((S) * 64 + lg * 16) ^ ((rh_ & 7) << 4)));                \
  } while (0)

  // prologue: tile0 all 4 halves, tile1 first 3 halves -> 14 loads; drain to 6 (tile0 done)
  HSTAGE(0, 0, 0); HSTAGE(0, 1, 0); HSTAGE(0, 1, 1); HSTAGE(0, 0, 1);
  HSTAGE(1, 0, 0); HSTAGE(1, 1, 0); HSTAGE(1, 1, 1);
  asm volatile("s_waitcnt vmcnt(6)" ::: "memory");
  __builtin_amdgcn_s_barrier();

  bf16x8 af[4][2], bf[4][2];

#pragma unroll 2
  for (int t = 0; t < nkt; ++t) {
    const int p = t & 1;
    // ---- phase 0: ds_read A-h0 (m0-3) + B-h0 (n0-1); stage A-h1(t+1) ----
#pragma unroll
    for (int m = 0; m < 4; m++) { LDA_F(af[m][0], p, m, 0); LDA_F(af[m][1], p, m, 1); }
#pragma unroll
    for (int n = 0; n < 2; n++) { LDB_F(bf[n][0], p, n, 0); LDB_F(bf[n][1], p, n, 1); }
    if (t + 1 < nkt) HSTAGE(t + 1, 0, 1);
    __builtin_amdgcn_s_barrier();
    __builtin_amdgcn_s_setprio(1);
#pragma unroll
    for (int m = 0; m < 4; m++)
#pragma unroll
      for (int n = 0; n < 2; n++) {
        acc[m][n] = __builtin_amdgcn_mfma_f32_16x16x32_bf16(af[m][0], bf[n][0], acc[m][n], 0, 0, 0);
        acc[m][n] = __builtin_amdgcn_mfma_f32_16x16x32_bf16(af[m][1], bf[n][1], acc[m][n], 0, 0, 0);
      }
    __builtin_amdgcn_s_setprio(0);
    __builtin_amdgcn_s_barrier();
    // ---- phase 1: ds_read B-h1 (n2-3); stage A-h0(t+2) ----
#pragma unroll
    for (int n = 2; n < 4; n++) { LDB_F(bf[n][0], p, n, 0); LDB_F(bf[n][1], p, n, 1); }
    if (t + 2 < nkt) HSTAGE(t + 2, 0, 0);
    __builtin_amdgcn_s_barrier();
    __builtin_amdgcn_s_setprio(1);
#pragma unroll
    for (int m = 0; m < 4; m++)
#pragma unroll
      for (int n = 2; n < 4; n++) {
        acc[m][n] = __builtin_amdgcn_mfma_f32_16x16x32_bf16(af[m][0], bf[n][0], acc[m][n], 0, 0, 0);
        acc[m][n] = __builtin_amdgcn_mfma_f32_16x16x32_bf16(af[m][1], bf[n][1], acc[m][n], 0, 0, 0);
      }
    __builtin_amdgcn_s_setprio(0);
    __builtin_amdgcn_s_barrier();
    // ---- phase 2: ds_read A-h1 (m4-7, reuse af); stage B-h0(t+2) ----
#pragma unroll
    for (int m = 0; m < 4; m++) { LDA_F(af[m][0], p, m + 4, 0); LDA_F(af[m][1], p, m + 4, 1); }
    if (t + 2 < nkt) HSTAGE(t + 2, 1, 0);
    __builtin_amdgcn_s_barrier();
    __builtin_amdgcn_s_setprio(1);
#pragma unroll
    for (int m = 0; m < 4; m++)
#pragma unroll
      for (int n = 2; n < 4; n++) {
        acc[m + 4][n] = __builtin_amdgcn_mfma_f32_16x16x32_bf16(af[m][0], bf[n][0], acc[m + 4][n], 0, 0, 0);
        acc[m + 4][n] = __builtin_amdgcn_mfma_f32_16x16x32_bf16(af[m][1], bf[n][1], acc[m + 4][n], 0, 0, 0);
      }
    __builtin_amdgcn_s_setprio(0);
    __builtin_amdgcn_s_barrier();
    // ---- phase 3: stage B-h1(t+2); MFMA m4-7 x n0-1; boundary vmcnt + barrier ----
    if (t + 2 < nkt) HSTAGE(t + 2, 1, 1);
    __builtin_amdgcn_s_barrier();
    __builtin_amdgcn_s_setprio(1);
#pragma unroll
    for (int m = 0; m < 4; m++)
#pragma unroll
      for (int n = 0; n < 2; n++) {
        acc[m + 4][n] = __builtin_amdgcn_mfma_f32_16x16x32_bf16(af[m][0], bf[n][0], acc[m + 4][n], 0, 0, 0);
        acc[m + 4][n] = __builtin_amdgcn_mfma_f32_16x16x32_bf16(af[m][1], bf[n][1], acc[m + 4][n], 0, 0, 0);
      }
    __builtin_amdgcn_s_setprio(0);
    if (t < nkt - 2)       asm volatile("s_waitcnt vmcnt(6)" ::: "memory");
    else if (t == nkt - 2) asm volatile("s_waitcnt vmcnt(0)" ::: "memory");
    __builtin_amdgcn_s_barrier();
  }
#undef HSTAGE
#undef LDA_F
#undef LDB_F

  // epilogue: -0.5 * sum(relu(c)^2), wave-reduce, one atomic per wave
  float loc = 0.f;
#pragma unroll
  for (int i = 0; i < 8; i++)
#pragma unroll
    for (int j = 0; j < 4; j++)
#pragma unroll
      for (int r = 0; r < 4; r++) {
        float v = acc[i][j][r];
        loc += (v > 0.f) ? v * v : 0.f;
      }
#pragma unroll
  for (int mask = 32; mask; mask >>= 1) loc += __shfl_xor(loc, mask, 64);
  if (lane == 0) atomicAdd(out, -0.5f * loc);
}

// ---------------- scores + logsumexp: LDS-staged, XCD-local, 3-deep ring ----------------
// grid (z=24, qt=32): linear block id = qt*24 + z, and 24 % 8 == 0 -> XCD = z % 8.
// All 32 blocks of a head run on ONE XCD; per-XCD k working set = 3 heads x 256 KB
// = 768 KB -> L2-resident. Block = 4 waves x 16 q-rows = 64 rows, all 2048 keys.
// k tiles (128 keys x 64 d = 16 KB contiguous) through a 3-deep LDS ring staged with
// global_load_lds; counted vmcnt(4) + raw s_barrier (newest stage stays in flight --
// no full drain). exp2-domain (beta*log2e folded into Wq): native v_exp_f32.
__global__ __launch_bounds__(256) void scores_lse(
    const u16* __restrict__ qB, const u16* __restrict__ kB, float* __restrict__ out)
{
  __shared__ __align__(16) u16 kbuf[3][128 * 64];   // 3 x 16KB ring
  const int z  = blockIdx.x;          // b*12+h
  const int qt = blockIdx.y;
  const int tid = threadIdx.x, lane = tid & 63, w = tid >> 6;
  const int l15 = lane & 15, lg = lane >> 4;

  // q fragments in registers (A operand: row = lane&15 = q-row within the wave's 16)
  const u16* qp = qB + ((size_t)z * 2048 + qt * 64 + w * 16 + l15) * 64 + lg * 8;
  bf16x8 qf0 = *(const bf16x8*)qp;          // dims 0..31 slice
  bf16x8 qf1 = *(const bf16x8*)(qp + 32);   // dims 32..63 slice

  // stage k-tile KB (rows = keys KB*128..+127, 128 B/row contiguous) into ring slot BUF
  // linear LDS dest + XOR-pre-swizzled source chunk; readers XOR by (row&7)<<4
#define KSTAGE(KB, BUF) do {                                                               \
    _Pragma("unroll")                                                                      \
    for (int i = 0; i < 4; i++) {                                                          \
      int rloc = i * 32 + w * 8 + (lane >> 3);                                             \
      int cb   = (((lane & 7) ^ (rloc & 7)) << 4);                                         \
      const char* src = (const char*)kB + ((size_t)z * 2048 + (KB) * 128 + rloc) * 128 + cb; \
      __builtin_amdgcn_global_load_lds((const __attribute__((address_space(1))) void*)src,  \
          (__attribute__((address_space(3))) void*)((char*)kbuf[(BUF)] + rloc * 128 + (lane & 7) * 16), 16, 0, 0); \
    }                                                                                      \
  } while (0)

  f32x4 sacc = {0.f, 0.f, 0.f, 0.f};   // reg r: q-row lg*4+r, key-col l15
  const f32x4 zz = {0.f, 0.f, 0.f, 0.f};

  KSTAGE(0, 0);
  KSTAGE(1, 1);
  asm volatile("s_waitcnt vmcnt(4)" ::: "memory");   // tile0 landed; tile1 in flight
  __builtin_amdgcn_s_barrier();
  __builtin_amdgcn_sched_barrier(0);

  const int NKB = 16;   // 2048 / 128
  for (int kb = 0; kb < NKB; ++kb) {
    // issue prefetch of kb+2 first (into the slot consumed at kb-1): max overlap
    if (kb + 2 < NKB) KSTAGE(kb + 2, (kb + 2) % 3);
    const char* cur = (const char*)kbuf[kb % 3];
#pragma unroll
    for (int g2 = 0; g2 < 8; ++g2) {
      int row = g2 * 16 + l15;
      const char* base = cur + row * 128;
      int sw = (row & 7) << 4;
      bf16x8 b0 = *(const bf16x8*)(base + ((lg * 16) ^ sw));
      bf16x8 b1 = *(const bf16x8*)(base + ((64 + lg * 16) ^ sw));
      f32x4 s = zz;
      s = __builtin_amdgcn_mfma_f32_16x16x32_bf16(qf0, b0, s, 0, 0, 0);
      s = __builtin_amdgcn_mfma_f32_16x16x32_bf16(qf1, b1, s, 0, 0, 0);
      sacc[0] += __builtin_amdgcn_exp2f(s[0]);
      sacc[1] += __builtin_amdgcn_exp2f(s[1]);
      sacc[2] += __builtin_amdgcn_exp2f(s[2]);
      sacc[3] += __builtin_amdgcn_exp2f(s[3]);
    }
    if (kb + 1 < NKB) {
      if (kb + 2 < NKB) asm volatile("s_waitcnt vmcnt(4)" ::: "memory");  // kb+1 done, kb+2 in flight
      else              asm volatile("s_waitcnt vmcnt(0)" ::: "memory");  // last stage done
      __builtin_amdgcn_s_barrier();
      __builtin_amdgcn_sched_barrier(0);
    }
  }
#undef KSTAGE

  // reduce over the 16 key-columns (lanes sharing lg)
#pragma unroll
  for (int mask = 8; mask; mask >>= 1) {
    sacc[0] += __shfl_xor(sacc[0], mask, 64);
    sacc[1] += __shfl_xor(sacc[1], mask, 64);
    sacc[2] += __shfl_xor(sacc[2], mask, 64);
    sacc[3] += __shfl_xor(sacc[3], mask, 64);
  }
  float part = 0.f;
  if (l15 == 0) {
    // v_log_f32 is natively log2
    part = __builtin_amdgcn_logf(sacc[0]) + __builtin_amdgcn_logf(sacc[1]) +
           __builtin_amdgcn_logf(sacc[2]) + __builtin_amdgcn_logf(sacc[3]);
  }
  part += __shfl_xor(part, 16, 64);
  part += __shfl_xor(part, 32, 64);
  // e_attn = -(1/beta)*sum(ln(sumexp)) = -8*ln2*sum(log2(sum2exp))
  if (lane == 0) atomicAdd(out, -5.5451774444795625f * part);
}

extern "C" void kernel_launch(void* const* d_in, const int* in_sizes, int n_in,
                              void* d_out, int out_size, void* d_ws, size_t ws_size,
                              hipStream_t stream)
{
  const float* g   = (const float*)d_in[0];
  const float* Wq  = (const float*)d_in[1];
  const float* Wk  = (const float*)d_in[2];
  const float* Whn = (const float*)d_in[3];
  float* out = (float*)d_out;
  char* ws = (char*)d_ws;

  u16* gB   = (u16*)(ws + OFF_GB);
  u16* wqB  = (u16*)(ws + OFF_WQB);
  u16* wkB  = (u16*)(ws + OFF_WKB);
  u16* whnB = (u16*)(ws + OFF_WHNB);
  u16* qB   = (u16*)(ws + OFF_QB);
  u16* kB   = (u16*)(ws + OFF_KB);

  (void)hipMemsetAsync(out, 0, sizeof(float), stream);

  convert_all<<<2048, 256, 0, stream>>>(g, Wq, Wk, Whn, gB, wqB, wkB, whnB);
  // q and k projections fused in one launch: grid.y 0..5 -> q, 6..11 -> k
  gemm_bt<<<dim3(32, 12), 256, 0, stream>>>(gB, wqB, wkB, qB, kB, 1024);
  // Hopfield energy: 256^2 8-phase
  hop_gemm8<<<dim3(16, 16), 512, 0, stream>>>(gB, whnB, out);
  // attention logsumexp (LDS-staged, XCD-local, 3-deep ring)
  scores_lse<<<dim3(24, 32), 256, 0, stream>>>(qB, kB, out);
}

// Round 7
// 205.550 us; speedup vs baseline: 1.3489x; 1.0142x over previous
//
#include <hip/hip_runtime.h>
#include <hip/hip_bf16.h>

typedef __attribute__((ext_vector_type(4))) float f32x4;
typedef __attribute__((ext_vector_type(8))) short bf16x8;   // 8 bf16 = 4 VGPRs
typedef unsigned short u16;
typedef __attribute__((ext_vector_type(4))) u16 u16x4;

// Problem constants
// g [2,2048,1024] f32 ; Wq/Wk [12,64,1024] f32 ; Whn [4096,1024] f32 ; out = scalar f32

// workspace layout (bytes)
#define OFF_GB    ((size_t)0)                    // g bf16      [4096][1024]  8388608
#define OFF_WQB   ((size_t)8388608)              // (beta*log2e)*Wq bf16 [768][1024]
#define OFF_WKB   ((size_t)(8388608+1572864))    // Wk bf16      [768][1024]
#define OFF_WHNB  ((size_t)(8388608+2*1572864))  // Whn bf16    [4096][1024]  8388608
#define OFF_QB    (OFF_WHNB + 8388608)           // q bf16 [24][2048][64] per-head
#define OFF_KB    (OFF_QB + 6291456)             // k bf16 [24][2048][64] per-head

__device__ __forceinline__ u16 f2bf(float f) {
  union { float f; unsigned u; } x; x.f = f;
  unsigned u = x.u;
  u += 0x7fffu + ((u >> 16) & 1u);   // RNE
  return (u16)(u >> 16);
}

// ---------------- fused f32 -> bf16 conversion (beta*log2e folded into Wq) ----------------
__global__ __launch_bounds__(256) void convert_all(
    const float* __restrict__ g, const float* __restrict__ wq,
    const float* __restrict__ wk, const float* __restrict__ whn,
    u16* __restrict__ gB, u16* __restrict__ wqB, u16* __restrict__ wkB, u16* __restrict__ whnB)
{
  const int NG = 1048576;   // 4194304/4 float4 quads
  const int NW = 196608;    // 786432/4
  const int total = NG + 2 * NW + NG;
  for (int i = blockIdx.x * blockDim.x + threadIdx.x; i < total; i += gridDim.x * blockDim.x) {
    const float4* src; u16* dst; int j; float scale = 1.0f;
    if (i < NG)              { src = (const float4*)g;   dst = gB;   j = i; }
    else if (i < NG + NW)    { src = (const float4*)wq;  dst = wqB;  j = i - NG;
                               scale = 0.125f * 1.44269504089f; }   // beta * log2(e)
    else if (i < NG + 2*NW)  { src = (const float4*)wk;  dst = wkB;  j = i - NG - NW; }
    else                     { src = (const float4*)whn; dst = whnB; j = i - NG - 2*NW; }
    float4 v = src[j];
    u16x4 o;
    o.x = f2bf(v.x * scale); o.y = f2bf(v.y * scale);
    o.z = f2bf(v.z * scale); o.w = f2bf(v.w * scale);
    *(u16x4*)(dst + (size_t)j * 4) = o;
  }
}

// ---------------- 128x128 tile GEMM (m97 structure), q/k projection ----------------
// XCD-chunked 1D grid (384 blocks): xcd = bid&7 owns bm in [ (xcd>>1)*8, +8 ),
// bn in [ (xcd&1)*6, +6 ) -> per-XCD L2 set = 2MB A + 1.5MB B < 4MB.
// bn<6 -> Wq->qB, else Wk->kB; store bf16 into per-head layout [z][n][64]
__global__ __launch_bounds__(256) void gemm_bt(
    const u16* __restrict__ A, const u16* __restrict__ B0, const u16* __restrict__ B1,
    u16* __restrict__ C0, u16* __restrict__ C1, int K)
{
  __shared__ u16 lA[128 * 64];
  __shared__ u16 lB[128 * 64];
  const int tid = threadIdx.x;
  const int lane = tid & 63;
  const int w = tid >> 6;          // wave 0..3
  const int bid = blockIdx.x;
  const int xcd = bid & 7, idx = bid >> 3;          // idx 0..47
  const int bm = ((xcd >> 1) << 3) + (idx & 7);     // 0..31
  const int bn = (xcd & 1) * 6 + (idx >> 3);        // 0..11

  const u16* Bp; u16* Cp; int bcol0;
  if (bn < 6) { Bp = B0; Cp = C0; bcol0 = bn * 128; }
  else        { Bp = B1; Cp = C1; bcol0 = (bn - 6) * 128; }
  const int arow0 = bm * 128;
  const int wr = w >> 1, wc = w & 1;
  const int l15 = lane & 15, lg = lane >> 4;

  f32x4 acc[4][4];
  const f32x4 zz = {0.f, 0.f, 0.f, 0.f};
#pragma unroll
  for (int m = 0; m < 4; m++)
#pragma unroll
    for (int n = 0; n < 4; n++) acc[m][n] = zz;

#define STAGE(KT) do {                                                                     \
    _Pragma("unroll")                                                                      \
    for (int i = 0; i < 4; i++) {                                                          \
      int rloc = w * 32 + i * 8 + (lane >> 3);                                             \
      int cb   = (((lane & 7) ^ (rloc & 7)) << 4);                                         \
      const char* srcA = (const char*)A + (((size_t)(arow0 + rloc)) * K + (KT) * 64) * 2 + cb; \
      __builtin_amdgcn_global_load_lds((const __attribute__((address_space(1))) void*)srcA, \
          (__attribute__((address_space(3))) void*)((char*)lA + (w * 32 + i * 8) * 128), 16, 0, 0); \
      const char* srcB = (const char*)Bp + (((size_t)(bcol0 + rloc)) * K + (KT) * 64) * 2 + cb; \
      __builtin_amdgcn_global_load_lds((const __attribute__((address_space(1))) void*)srcB, \
          (__attribute__((address_space(3))) void*)((char*)lB + (w * 32 + i * 8) * 128), 16, 0, 0); \
    }                                                                                      \
  } while (0)

  STAGE(0);
  const int nkt = K / 64;
  for (int kt = 0; kt < nkt; ++kt) {
    __syncthreads();
    bf16x8 a0[4], a1[4], b0[4], b1[4];
#pragma unroll
    for (int m = 0; m < 4; m++) {
      int row = wr * 64 + m * 16 + l15;
      const char* base = (const char*)lA + row * 128;
      int sw = (row & 7) << 4;
      a0[m] = *(const bf16x8*)(base + ((lg * 16) ^ sw));
      a1[m] = *(const bf16x8*)(base + ((64 + lg * 16) ^ sw));
    }
#pragma unroll
    for (int n = 0; n < 4; n++) {
      int row = wc * 64 + n * 16 + l15;
      const char* base = (const char*)lB + row * 128;
      int sw = (row & 7) << 4;
      b0[n] = *(const bf16x8*)(base + ((lg * 16) ^ sw));
      b1[n] = *(const bf16x8*)(base + ((64 + lg * 16) ^ sw));
    }
    __syncthreads();
    if (kt + 1 < nkt) STAGE(kt + 1);
#pragma unroll
    for (int m = 0; m < 4; m++)
#pragma unroll
      for (int n = 0; n < 4; n++) {
        acc[m][n] = __builtin_amdgcn_mfma_f32_16x16x32_bf16(a0[m], b0[n], acc[m][n], 0, 0, 0);
        acc[m][n] = __builtin_amdgcn_mfma_f32_16x16x32_bf16(a1[m], b1[n], acc[m][n], 0, 0, 0);
      }
  }
  // C/D layout (m89-verified): col = lane&15, row = (lane>>4)*4 + reg
  // per-head dst: row = b*2048+nn, col = h*64+d  ->  ((b*12+h)*2048 + nn)*64 + d
#pragma unroll
  for (int m = 0; m < 4; m++)
#pragma unroll
    for (int n = 0; n < 4; n++)
#pragma unroll
      for (int r = 0; r < 4; r++) {
        int row = arow0 + wr * 64 + m * 16 + lg * 4 + r;
        int col = bcol0 + wc * 64 + n * 16 + l15;
        size_t dst = ((((size_t)(row >> 11) * 12 + (col >> 6)) << 11) + (row & 2047)) * 64 + (col & 63);
        Cp[dst] = f2bf(acc[m][n][r]);
      }
#undef STAGE
}

// ---------------- Hopfield energy: 256x256-tile 8-phase GEMM (T1+T2+T3+T4+T5) ----------------
// XCD-chunked 1D grid (256 blocks): xcd = bid&7 owns a contiguous 4bm x 8bn chunk of the
// 16x16 tile grid -> per-XCD, per-K-tile distinct staging = 384KB (L2-resident); all 32
// blocks of an XCD are co-resident (1 block/CU) and share panel lines in L2.
__global__ __launch_bounds__(512, 2) void hop_gemm8(
    const u16* __restrict__ A, const u16* __restrict__ Bm, float* __restrict__ out)
{
  __shared__ __align__(16) u16 lds[2][2][2][128][64];   // [buf][mat][half][row][col]
  const int tid = threadIdx.x;
  const int lane = tid & 63, w = tid >> 6;
  const int wr = w >> 2, wc = w & 3;
  const int l15 = lane & 15, lg = lane >> 4;
  const int bid = blockIdx.x;
  const int xcd = bid & 7, idx = bid >> 3;            // idx 0..31
  const int am0 = (((xcd >> 1) << 2) + (idx & 3)) * 256;   // bm 0..15
  const int bn0 = (((xcd & 1) << 3) + (idx >> 2)) * 256;   // bn 0..15
  constexpr int nkt = 16;   // K = 1024, BK = 64

  f32x4 acc[8][4];
  const f32x4 zz = {0.f, 0.f, 0.f, 0.f};
#pragma unroll
  for (int i = 0; i < 8; i++)
#pragma unroll
    for (int j = 0; j < 4; j++) acc[i][j] = zz;

#define HSTAGE(KT, MAT, H) do {                                                            \
    const u16* s_ = (MAT) ? Bm : A;                                                        \
    int rb_ = ((MAT) ? bn0 : am0) + (H) * 128;                                             \
    char* d0_ = (char*)&lds[(KT) & 1][(MAT)][(H)][0][0];                                   \
    _Pragma("unroll")                                                                      \
    for (int q_ = 0; q_ < 2; q_++) {                                                       \
      int r_ = q_ * 64 + (tid >> 3);                                                       \
      int cb_ = ((tid & 7) * 16) ^ ((r_ & 7) << 4);                                        \
      const char* g_ = (const char*)s_ + (size_t)(rb_ + r_) * 2048 + (KT) * 128 + cb_;     \
      __builtin_amdgcn_global_load_lds((const __attribute__((address_space(1))) void*)g_,  \
          (__attribute__((address_space(3))) void*)(d0_ + q_ * 8192 + tid * 16), 16, 0, 0);\
    }                                                                                      \
  } while (0)

#define LDA_F(DST, P, I, S) do {                                                           \
    int rh_ = ((I) & 3) * 32 + wr * 16 + l15;                                              \
    const char* b_ = (const char*)&lds[(P)][0][(I) >> 2][0][0] + rh_ * 128;                \
    DST = *(const bf16x8*)(b_ + (((S) * 64 + lg * 16) ^ ((rh_ & 7) << 4)));                \
  } while (0)
#define LDB_F(DST, P, J, S) do {                                                           \
    int rh_ = ((J) & 1) * 64 + wc * 16 + l15;                                              \
    const char* b_ = (const char*)&lds[(P)][1][(J) >> 1][0][0] + rh_ * 128;                \
    DST = *(const bf16x8*)(b_ + (((S) * 64 + lg * 16) ^ ((rh_ & 7) << 4)));                \
  } while (0)

  // prologue: tile0 all 4 halves, tile1 first 3 halves -> 14 loads; drain to 6 (tile0 done)
  HSTAGE(0, 0, 0); HSTAGE(0, 1, 0); HSTAGE(0, 1, 1); HSTAGE(0, 0, 1);
  HSTAGE(1, 0, 0); HSTAGE(1, 1, 0); HSTAGE(1, 1, 1);
  asm volatile("s_waitcnt vmcnt(6)" ::: "memory");
  __builtin_amdgcn_s_barrier();

  bf16x8 af[4][2], bf[4][2];

#pragma unroll 2
  for (int t = 0; t < nkt; ++t) {
    const int p = t & 1;
    // ---- phase 0: ds_read A-h0 (m0-3) + B-h0 (n0-1); stage A-h1(t+1) ----
#pragma unroll
    for (int m = 0; m < 4; m++) { LDA_F(af[m][0], p, m, 0); LDA_F(af[m][1], p, m, 1); }
#pragma unroll
    for (int n = 0; n < 2; n++) { LDB_F(bf[n][0], p, n, 0); LDB_F(bf[n][1], p, n, 1); }
    if (t + 1 < nkt) HSTAGE(t + 1, 0, 1);
    __builtin_amdgcn_s_barrier();
    __builtin_amdgcn_s_setprio(1);
#pragma unroll
    for (int m = 0; m < 4; m++)
#pragma unroll
      for (int n = 0; n < 2; n++) {
        acc[m][n] = __builtin_amdgcn_mfma_f32_16x16x32_bf16(af[m][0], bf[n][0], acc[m][n], 0, 0, 0);
        acc[m][n] = __builtin_amdgcn_mfma_f32_16x16x32_bf16(af[m][1], bf[n][1], acc[m][n], 0, 0, 0);
      }
    __builtin_amdgcn_s_setprio(0);
    __builtin_amdgcn_s_barrier();
    // ---- phase 1: ds_read B-h1 (n2-3); stage A-h0(t+2) ----
#pragma unroll
    for (int n = 2; n < 4; n++) { LDB_F(bf[n][0], p, n, 0); LDB_F(bf[n][1], p, n, 1); }
    if (t + 2 < nkt) HSTAGE(t + 2, 0, 0);
    __builtin_amdgcn_s_barrier();
    __builtin_amdgcn_s_setprio(1);
#pragma unroll
    for (int m = 0; m < 4; m++)
#pragma unroll
      for (int n = 2; n < 4; n++) {
        acc[m][n] = __builtin_amdgcn_mfma_f32_16x16x32_bf16(af[m][0], bf[n][0], acc[m][n], 0, 0, 0);
        acc[m][n] = __builtin_amdgcn_mfma_f32_16x16x32_bf16(af[m][1], bf[n][1], acc[m][n], 0, 0, 0);
      }
    __builtin_amdgcn_s_setprio(0);
    __builtin_amdgcn_s_barrier();
    // ---- phase 2: ds_read A-h1 (m4-7, reuse af); stage B-h0(t+2) ----
#pragma unroll
    for (int m = 0; m < 4; m++) { LDA_F(af[m][0], p, m + 4, 0); LDA_F(af[m][1], p, m + 4, 1); }
    if (t + 2 < nkt) HSTAGE(t + 2, 1, 0);
    __builtin_amdgcn_s_barrier();
    __builtin_amdgcn_s_setprio(1);
#pragma unroll
    for (int m = 0; m < 4; m++)
#pragma unroll
      for (int n = 2; n < 4; n++) {
        acc[m + 4][n] = __builtin_amdgcn_mfma_f32_16x16x32_bf16(af[m][0], bf[n][0], acc[m + 4][n], 0, 0, 0);
        acc[m + 4][n] = __builtin_amdgcn_mfma_f32_16x16x32_bf16(af[m][1], bf[n][1], acc[m + 4][n], 0, 0, 0);
      }
    __builtin_amdgcn_s_setprio(0);
    __builtin_amdgcn_s_barrier();
    // ---- phase 3: stage B-h1(t+2); MFMA m4-7 x n0-1; boundary vmcnt + barrier ----
    if (t + 2 < nkt) HSTAGE(t + 2, 1, 1);
    __builtin_amdgcn_s_barrier();
    __builtin_amdgcn_s_setprio(1);
#pragma unroll
    for (int m = 0; m < 4; m++)
#pragma unroll
      for (int n = 0; n < 2; n++) {
        acc[m + 4][n] = __builtin_amdgcn_mfma_f32_16x16x32_bf16(af[m][0], bf[n][0], acc[m + 4][n], 0, 0, 0);
        acc[m + 4][n] = __builtin_amdgcn_mfma_f32_16x16x32_bf16(af[m][1], bf[n][1], acc[m + 4][n], 0, 0, 0);
      }
    __builtin_amdgcn_s_setprio(0);
    if (t < nkt - 2)       asm volatile("s_waitcnt vmcnt(6)" ::: "memory");
    else if (t == nkt - 2) asm volatile("s_waitcnt vmcnt(0)" ::: "memory");
    __builtin_amdgcn_s_barrier();
  }
#undef HSTAGE
#undef LDA_F
#undef LDB_F

  // epilogue: -0.5 * sum(relu(c)^2), wave-reduce, one atomic per wave
  float loc = 0.f;
#pragma unroll
  for (int i = 0; i < 8; i++)
#pragma unroll
    for (int j = 0; j < 4; j++)
#pragma unroll
      for (int r = 0; r < 4; r++) {
        float v = acc[i][j][r];
        loc += (v > 0.f) ? v * v : 0.f;
      }
#pragma unroll
  for (int mask = 32; mask; mask >>= 1) loc += __shfl_xor(loc, mask, 64);
  if (lane == 0) atomicAdd(out, -0.5f * loc);
}

// ---------------- scores + logsumexp: LDS-staged, XCD-local, 3-deep ring ----------------
// grid (z=24, qt=32): linear block id = qt*24 + z, 24 % 8 == 0 -> XCD = z % 8.
__global__ __launch_bounds__(256) void scores_lse(
    const u16* __restrict__ qB, const u16* __restrict__ kB, float* __restrict__ out)
{
  __shared__ __align__(16) u16 kbuf[3][128 * 64];   // 3 x 16KB ring
  const int z  = blockIdx.x;          // b*12+h
  const int qt = blockIdx.y;
  const int tid = threadIdx.x, lane = tid & 63, w = tid >> 6;
  const int l15 = lane & 15, lg = lane >> 4;

  // q fragments in registers (A operand: row = lane&15 = q-row within the wave's 16)
  const u16* qp = qB + ((size_t)z * 2048 + qt * 64 + w * 16 + l15) * 64 + lg * 8;
  bf16x8 qf0 = *(const bf16x8*)qp;          // dims 0..31 slice
  bf16x8 qf1 = *(const bf16x8*)(qp + 32);   // dims 32..63 slice

#define KSTAGE(KB, BUF) do {                                                               \
    _Pragma("unroll")                                                                      \
    for (int i = 0; i < 4; i++) {                                                          \
      int rloc = i * 32 + w * 8 + (lane >> 3);                                             \
      int cb   = (((lane & 7) ^ (rloc & 7)) << 4);                                         \
      const char* src = (const char*)kB + ((size_t)z * 2048 + (KB) * 128 + rloc) * 128 + cb; \
      __builtin_amdgcn_global_load_lds((const __attribute__((address_space(1))) void*)src,  \
          (__attribute__((address_space(3))) void*)((char*)kbuf[(BUF)] + rloc * 128 + (lane & 7) * 16), 16, 0, 0); \
    }                                                                                      \
  } while (0)

  f32x4 sacc = {0.f, 0.f, 0.f, 0.f};   // reg r: q-row lg*4+r, key-col l15
  const f32x4 zz = {0.f, 0.f, 0.f, 0.f};

  KSTAGE(0, 0);
  KSTAGE(1, 1);
  asm volatile("s_waitcnt vmcnt(4)" ::: "memory");   // tile0 landed; tile1 in flight
  __builtin_amdgcn_s_barrier();
  __builtin_amdgcn_sched_barrier(0);

  const int NKB = 16;   // 2048 / 128
  for (int kb = 0; kb < NKB; ++kb) {
    // issue prefetch of kb+2 first (into the slot consumed at kb-1): max overlap
    if (kb + 2 < NKB) KSTAGE(kb + 2, (kb + 2) % 3);
    const char* cur = (const char*)kbuf[kb % 3];
#pragma unroll
    for (int g2 = 0; g2 < 8; ++g2) {
      int row = g2 * 16 + l15;
      const char* base = cur + row * 128;
      int sw = (row & 7) << 4;
      bf16x8 b0 = *(const bf16x8*)(base + ((lg * 16) ^ sw));
      bf16x8 b1 = *(const bf16x8*)(base + ((64 + lg * 16) ^ sw));
      f32x4 s = zz;
      s = __builtin_amdgcn_mfma_f32_16x16x32_bf16(qf0, b0, s, 0, 0, 0);
      s = __builtin_amdgcn_mfma_f32_16x16x32_bf16(qf1, b1, s, 0, 0, 0);
      sacc[0] += __builtin_amdgcn_exp2f(s[0]);
      sacc[1] += __builtin_amdgcn_exp2f(s[1]);
      sacc[2] += __builtin_amdgcn_exp2f(s[2]);
      sacc[3] += __builtin_amdgcn_exp2f(s[3]);
    }
    if (kb + 1 < NKB) {
      if (kb + 2 < NKB) asm volatile("s_waitcnt vmcnt(4)" ::: "memory");  // kb+1 done, kb+2 in flight
      else              asm volatile("s_waitcnt vmcnt(0)" ::: "memory");  // last stage done
      __builtin_amdgcn_s_barrier();
      __builtin_amdgcn_sched_barrier(0);
    }
  }
#undef KSTAGE

  // reduce over the 16 key-columns (lanes sharing lg)
#pragma unroll
  for (int mask = 8; mask; mask >>= 1) {
    sacc[0] += __shfl_xor(sacc[0], mask, 64);
    sacc[1] += __shfl_xor(sacc[1], mask, 64);
    sacc[2] += __shfl_xor(sacc[2], mask, 64);
    sacc[3] += __shfl_xor(sacc[3], mask, 64);
  }
  float part = 0.f;
  if (l15 == 0) {
    // v_log_f32 is natively log2
    part = __builtin_amdgcn_logf(sacc[0]) + __builtin_amdgcn_logf(sacc[1]) +
           __builtin_amdgcn_logf(sacc[2]) + __builtin_amdgcn_logf(sacc[3]);
  }
  part += __shfl_xor(part, 16, 64);
  part += __shfl_xor(part, 32, 64);
  // e_attn = -(1/beta)*sum(ln(sumexp)) = -8*ln2*sum(log2(sum2exp))
  if (lane == 0) atomicAdd(out, -5.5451774444795625f * part);
}

extern "C" void kernel_launch(void* const* d_in, const int* in_sizes, int n_in,
                              void* d_out, int out_size, void* d_ws, size_t ws_size,
                              hipStream_t stream)
{
  const float* g   = (const float*)d_in[0];
  const float* Wq  = (const float*)d_in[1];
  const float* Wk  = (const float*)d_in[2];
  const float* Whn = (const float*)d_in[3];
  float* out = (float*)d_out;
  char* ws = (char*)d_ws;

  u16* gB   = (u16*)(ws + OFF_GB);
  u16* wqB  = (u16*)(ws + OFF_WQB);
  u16* wkB  = (u16*)(ws + OFF_WKB);
  u16* whnB = (u16*)(ws + OFF_WHNB);
  u16* qB   = (u16*)(ws + OFF_QB);
  u16* kB   = (u16*)(ws + OFF_KB);

  (void)hipMemsetAsync(out, 0, sizeof(float), stream);

  convert_all<<<2048, 256, 0, stream>>>(g, Wq, Wk, Whn, gB, wqB, wkB, whnB);
  // q and k projections (XCD-chunked 1D grid: bn 0..5 -> q, 6..11 -> k)
  gemm_bt<<<384, 256, 0, stream>>>(gB, wqB, wkB, qB, kB, 1024);
  // Hopfield energy: 256^2 8-phase, XCD-chunked
  hop_gemm8<<<256, 512, 0, stream>>>(gB, whnB, out);
  // attention logsumexp (LDS-staged, XCD-local, 3-deep ring)
  scores_lse<<<dim3(24, 32), 256, 0, stream>>>(qB, kB, out);
}